// Round 4
// baseline (206.067 us; speedup 1.0000x reference)
//
#include <hip/hip_runtime.h>
#include <hip/hip_bf16.h>

// partial row layout (12 floats, 3 x float4):
//   [0]=cls [1]=noobj [2]=S0 [3]=S1_p0 [4]=S2_p0 [5]=S1_p1 [6]=S2_p1
//   [7]=reg_p0 [8]=reg_p1 [9]=imax (int bitcast) [10..11] pad
#define NQ   9
#define ROW  12
#define TILE 256

__global__ __launch_bounds__(256) void yolo_partial_kernel(
    const float* __restrict__ pred,
    const float* __restrict__ tbox,
    const float* __restrict__ tcls,
    const int*   __restrict__ obj,
    float* __restrict__ partial,     // [gridDim.x * ROW]
    int M, int ntiles)
{
    __shared__ float sp[TILE * 30];  // 30720 B -> 5 blocks/CU
    const int t = threadIdx.x;

    float acc[NQ];
#pragma unroll
    for (int q = 0; q < NQ; ++q) acc[q] = 0.f;
    int imax = -1;

    for (int tile = blockIdx.x; tile < ntiles; tile += gridDim.x) {
        const int c0 = tile * TILE;
        const int nc = min(TILE, M - c0);

        __syncthreads();   // protect sp from previous iteration's readers

        if (nc == TILE) {
            const int cell = c0 + t;
            // ---- issue ALL independent loads up front (max MLP) ----
            const int   o  = obj[cell];                                  // coalesced
            const float4 tb = reinterpret_cast<const float4*>(tbox)[cell]; // coalesced
            const float4* cv = reinterpret_cast<const float4*>(tcls + (size_t)c0 * 20);
            float4 tc[5];
#pragma unroll
            for (int j = 0; j < 5; ++j) tc[j] = cv[j * 256 + t];
            // pred tile staging: identity float4 copy, fully coalesced
            const float4* pv = reinterpret_cast<const float4*>(pred + (size_t)c0 * 30);
            float4* spv = reinterpret_cast<float4*>(sp);
#pragma unroll
            for (int j = 0; j < 7; ++j) spv[j * 256 + t] = pv[j * 256 + t];
            if (t < 128) spv[1792 + t] = pv[1792 + t];
            __syncthreads();

            // ---- cls phase: tcls from regs, pred ch10-29 from LDS ----
#pragma unroll
            for (int j = 0; j < 5; ++j) {
                int i = j * 256 + t;
                int cl2 = i / 5;                 // 5 float4 per cell
                int ch  = (i - cl2 * 5) * 4;
                const float* s = sp + cl2 * 30 + 10 + ch;
                float4 v = tc[j];
                float d0 = s[0] - v.x, d1 = s[1] - v.y;
                float d2 = s[2] - v.z, d3 = s[3] - v.w;
                acc[0] += d0 * d0 + d1 * d1 + d2 * d2 + d3 * d3;
            }

            // ---- per-cell phase: thread t owns cell c0+t; tb/o already in regs ----
            const float* s = sp + t * 30;
            const float p0c = s[4];
            if (!o) {
                acc[1] += p0c * p0c;             // L_NOOBJ * 2 == 1.0
            } else {
                acc[2] += 1.f;
                acc[3] += p0c;
                acc[4] += p0c * p0c;
                const float p1c = s[9];
                acc[5] += p1c;
                acc[6] += p1c * p1c;
                const float st2 = sqrtf(tb.z), st3 = sqrtf(tb.w);
                {
                    float dx = s[0] - tb.x, dy = s[1] - tb.y;
                    float dw = sqrtf(s[2]) - st2, dh = sqrtf(s[3]) - st3;
                    acc[7] += dx * dx + dy * dy + dw * dw + dh * dh;
                }
                {
                    float dx = s[5] - tb.x, dy = s[6] - tb.y;
                    float dw = sqrtf(s[7]) - st2, dh = sqrtf(s[8]) - st3;
                    acc[8] += dx * dx + dy * dy + dw * dw + dh * dh;
                }
                imax = cell;
            }
        } else {
            // scalar tail (unused for M = 3136*256, kept for safety)
            for (int e = t; e < nc * 30; e += 256) sp[e] = pred[(size_t)c0 * 30 + e];
            __syncthreads();
            for (int e = t; e < nc * 20; e += 256) {
                int cl2 = e / 20, ch = e - cl2 * 20;
                float d = sp[cl2 * 30 + 10 + ch] - tcls[(size_t)c0 * 20 + e];
                acc[0] += d * d;
            }
            if (t < nc) {
                const int cell = c0 + t;
                const float* s = sp + t * 30;
                const float p0c = s[4];
                if (!obj[cell]) {
                    acc[1] += p0c * p0c;
                } else {
                    float4 tb = reinterpret_cast<const float4*>(tbox)[cell];
                    acc[2] += 1.f; acc[3] += p0c; acc[4] += p0c * p0c;
                    const float p1c = s[9];
                    acc[5] += p1c; acc[6] += p1c * p1c;
                    const float st2 = sqrtf(tb.z), st3 = sqrtf(tb.w);
                    float dx = s[0] - tb.x, dy = s[1] - tb.y;
                    float dw = sqrtf(s[2]) - st2, dh = sqrtf(s[3]) - st3;
                    acc[7] += dx * dx + dy * dy + dw * dw + dh * dh;
                    dx = s[5] - tb.x; dy = s[6] - tb.y;
                    dw = sqrtf(s[7]) - st2; dh = sqrtf(s[8]) - st3;
                    acc[8] += dx * dx + dy * dy + dw * dw + dh * dh;
                    imax = cell;
                }
            }
        }
    }

    // ---- wave (64-lane) shuffle reduction ----
#pragma unroll
    for (int off = 32; off > 0; off >>= 1) {
#pragma unroll
        for (int q = 0; q < NQ; ++q) acc[q] += __shfl_down(acc[q], off, 64);
        imax = max(imax, __shfl_down(imax, off, 64));
    }

    __shared__ float sred[4][NQ];
    __shared__ int   sidx[4];
    const int lane = t & 63;
    const int wid  = t >> 6;
    if (lane == 0) {
#pragma unroll
        for (int q = 0; q < NQ; ++q) sred[wid][q] = acc[q];
        sidx[wid] = imax;
    }
    __syncthreads();

    if (t == 0) {
        float tot[NQ];
        int   mx = sidx[0];
#pragma unroll
        for (int q = 0; q < NQ; ++q) tot[q] = sred[0][q];
        for (int w = 1; w < 4; ++w) {
#pragma unroll
            for (int q = 0; q < NQ; ++q) tot[q] += sred[w][q];
            mx = max(mx, sidx[w]);
        }
        float4* row = reinterpret_cast<float4*>(partial + (size_t)blockIdx.x * ROW);
        row[0] = make_float4(tot[0], tot[1], tot[2], tot[3]);
        row[1] = make_float4(tot[4], tot[5], tot[6], tot[7]);
        row[2] = make_float4(tot[8], __int_as_float(mx), 0.f, 0.f);
    }
}

__global__ __launch_bounds__(256) void yolo_final_kernel(
    const float* __restrict__ pred,
    const float* __restrict__ tbox,
    const float* __restrict__ partial,
    float* __restrict__ out,
    int nrows, float invN)
{
    const int t = threadIdx.x;
    float acc[NQ];
#pragma unroll
    for (int q = 0; q < NQ; ++q) acc[q] = 0.f;
    int imax = -1;

    for (int r = t; r < nrows; r += 256) {
        const float4* row = reinterpret_cast<const float4*>(partial + (size_t)r * ROW);
        float4 a = row[0], b = row[1], c = row[2];
        acc[0] += a.x; acc[1] += a.y; acc[2] += a.z; acc[3] += a.w;
        acc[4] += b.x; acc[5] += b.y; acc[6] += b.z; acc[7] += b.w;
        acc[8] += c.x;
        imax = max(imax, __float_as_int(c.y));
    }

#pragma unroll
    for (int off = 32; off > 0; off >>= 1) {
#pragma unroll
        for (int q = 0; q < NQ; ++q) acc[q] += __shfl_down(acc[q], off, 64);
        imax = max(imax, __shfl_down(imax, off, 64));
    }

    __shared__ float sred[4][NQ];
    __shared__ int   sidx[4];
    const int lane = t & 63;
    const int wid  = t >> 6;
    if (lane == 0) {
#pragma unroll
        for (int q = 0; q < NQ; ++q) sred[wid][q] = acc[q];
        sidx[wid] = imax;
    }
    __syncthreads();

    if (t == 0) {
        float sums[NQ];
        int idx = sidx[0];
#pragma unroll
        for (int q = 0; q < NQ; ++q) sums[q] = sred[0][q];
        for (int w = 1; w < 4; ++w) {
#pragma unroll
            for (int q = 0; q < NQ; ++q) sums[q] += sred[w][q];
            idx = max(idx, sidx[w]);
        }

        const float* p  = pred + (size_t)idx * 30;
        const float* tb = tbox + (size_t)idx * 4;

        float b0[4], b1[4], bt[4];
        {
            float cx = p[0] / 14.f, cy = p[1] / 14.f;
            b0[0] = cx - 0.5f * p[2]; b0[1] = cy - 0.5f * p[3];
            b0[2] = cx + 0.5f * p[2]; b0[3] = cy + 0.5f * p[3];
        }
        {
            float cx = p[5] / 14.f, cy = p[6] / 14.f;
            b1[0] = cx - 0.5f * p[7]; b1[1] = cy - 0.5f * p[8];
            b1[2] = cx + 0.5f * p[7]; b1[3] = cy + 0.5f * p[8];
        }
        {
            float cx = tb[0] / 14.f, cy = tb[1] / 14.f;
            bt[0] = cx - 0.5f * tb[2]; bt[1] = cy - 0.5f * tb[3];
            bt[2] = cx + 0.5f * tb[2]; bt[3] = cy + 0.5f * tb[3];
        }
        auto iou = [](const float* a, const float* b) {
            float ltx = fmaxf(a[0], b[0]), lty = fmaxf(a[1], b[1]);
            float rbx = fminf(a[2], b[2]), rby = fminf(a[3], b[3]);
            float w = fmaxf(rbx - ltx, 0.f), h = fmaxf(rby - lty, 0.f);
            float inter = w * h;
            float a1 = (a[2] - a[0]) * (a[3] - a[1]);
            float a2 = (b[2] - b[0]) * (b[3] - b[1]);
            return inter / (a1 + a2 - inter);
        };
        float iou0 = iou(b0, bt), iou1 = iou(b1, bt);
        bool  m = iou0 > iou1;
        float c = m ? iou0 : iou1;

        float S0  = sums[2];
        float S1  = m ? sums[3] : sums[5];
        float S2  = m ? sums[4] : sums[6];
        float reg = m ? sums[7] : sums[8];

        float reg_loss   = 5.f * reg;                       // L_COORD
        float containing = S2 - 2.f * c * S1 + c * c * S0;  // sum obj*(conf-c)^2
        float noobj      = sums[1];
        float cls        = sums[0];
        float total      = cls + noobj + reg_loss + containing;

        out[0] = total * invN;
        out[1] = reg_loss * invN;
        out[2] = containing * invN;
        out[3] = noobj * invN;
        out[4] = cls * invN;
    }
}

extern "C" void kernel_launch(void* const* d_in, const int* in_sizes, int n_in,
                              void* d_out, int out_size, void* d_ws, size_t ws_size,
                              hipStream_t stream) {
    const float* pred = (const float*)d_in[0];
    const float* tbox = (const float*)d_in[1];
    const float* tcls = (const float*)d_in[2];
    const int*   obj  = (const int*)d_in[3];
    float* out = (float*)d_out;

    const int M = in_sizes[3];                  // BATCH * S * S
    const int N = in_sizes[0] / (14 * 14 * 30); // BATCH
    const int ntiles = (M + TILE - 1) / TILE;   // 3136

    // one private partial row per block; clamp to workspace capacity
    int nblk = ntiles;
    const int max_rows = (int)(ws_size / (ROW * sizeof(float)));
    if (nblk > max_rows) nblk = max_rows;
    if (nblk < 1) nblk = 1;

    float* partial = (float*)d_ws;

    yolo_partial_kernel<<<nblk, 256, 0, stream>>>(pred, tbox, tcls, obj, partial, M, ntiles);
    yolo_final_kernel<<<1, 256, 0, stream>>>(pred, tbox, partial, out, nblk, 1.f / (float)N);
}